// Round 8
// baseline (159.548 us; speedup 1.0000x reference)
//
#include <hip/hip_runtime.h>

#define DIM 1024
#define SEQ 2048
#define BATCH 2
#define NHEADS 16
#define HD 64
#define ROWS (BATCH * SEQ) // 4096

typedef __bf16 bf16x8 __attribute__((ext_vector_type(8)));
typedef __bf16 bf16x4 __attribute__((ext_vector_type(4)));
typedef float f32x4 __attribute__((ext_vector_type(4)));
typedef float f32x16 __attribute__((ext_vector_type(16)));
typedef unsigned u32x4 __attribute__((ext_vector_type(4)));

__device__ __forceinline__ f32x4 f4zero() {
    f32x4 z = {0.f, 0.f, 0.f, 0.f};
    return z;
}

__device__ __forceinline__ unsigned cvtpk(float lo, float hi) {
    unsigned r;
    asm("v_cvt_pk_bf16_f32 %0, %1, %2" : "=v"(r) : "v"(lo), "v"(hi));
    return r;
}

__device__ __forceinline__ void pl32swap(unsigned& a, unsigned& b) {
    asm volatile("v_permlane32_swap_b32 %0, %1" : "+v"(a), "+v"(b));
}

// slot base within one bh (32-row strips, 512-pos chunks):
// qp 0..15 -> 1 chunk, 16..31 -> 2, 32..47 -> 3, 48..63 -> 4 (160 total)
__device__ __forceinline__ int slot_base(int qp) {
    if (qp < 16) return qp;
    if (qp < 32) return 16 + 2 * (qp - 16);
    if (qp < 48) return 48 + 3 * (qp - 32);
    return 96 + 4 * (qp - 48);
}

#define GLOAD_LDS16(g, l)                                                                  \
    __builtin_amdgcn_global_load_lds((const __attribute__((address_space(1))) void*)(g),   \
                                     (__attribute__((address_space(3))) void*)(l), 16, 0, 0)

// ---------------- RMSNorm -> bf16 ----------------
__global__ __launch_bounds__(256) void rmsnorm_bf16(const float* __restrict__ x,
                                                    const float* __restrict__ w,
                                                    __bf16* __restrict__ xn) {
    int row = blockIdx.x;
    int t = threadIdx.x;
    float4 v = ((const float4*)(x + (size_t)row * DIM))[t];
    float ss = v.x * v.x + v.y * v.y + v.z * v.z + v.w * v.w;
#pragma unroll
    for (int off = 1; off < 64; off <<= 1) ss += __shfl_xor(ss, off);
    __shared__ float red[4];
    if ((t & 63) == 0) red[t >> 6] = ss;
    __syncthreads();
    ss = red[0] + red[1] + red[2] + red[3];
    float scale = rsqrtf(ss * (1.0f / DIM) + 1e-5f);
    float4 wv = ((const float4*)w)[t];
    bf16x4 o;
    o[0] = (__bf16)(v.x * scale * wv.x);
    o[1] = (__bf16)(v.y * scale * wv.y);
    o[2] = (__bf16)(v.z * scale * wv.z);
    o[3] = (__bf16)(v.w * scale * wv.w);
    *(bf16x4*)(xn + (size_t)row * DIM + t * 4) = o;
}

// ---------------- Weight convert + transpose: W[k][n] f32 -> Wt[n][k] bf16 ----------------
__global__ __launch_bounds__(256) void wcvt_kernel(const float* __restrict__ Wq,
                                                   const float* __restrict__ Wk,
                                                   const float* __restrict__ Wv,
                                                   const float* __restrict__ Wo,
                                                   __bf16* tq, __bf16* tk, __bf16* tv, __bf16* to_) {
    int z = blockIdx.z;
    const float* W = z == 0 ? Wq : z == 1 ? Wk : z == 2 ? Wv : Wo;
    __bf16* T = z == 0 ? tq : z == 1 ? tk : z == 2 ? tv : to_;
    __shared__ float tile[32][33];
    int n0 = blockIdx.x * 32, k0 = blockIdx.y * 32;
    int tx = threadIdx.x & 31, ty = threadIdx.x >> 5;
#pragma unroll
    for (int j = 0; j < 32; j += 8) tile[ty + j][tx] = W[(size_t)(k0 + ty + j) * DIM + n0 + tx];
    __syncthreads();
#pragma unroll
    for (int j = 0; j < 32; j += 8)
        T[(size_t)(n0 + ty + j) * DIM + k0 + tx] = (__bf16)tile[tx][ty + j];
}

// ---------------- RoPE table ----------------
__global__ __launch_bounds__(256) void rope_table_kernel(float* __restrict__ cosT,
                                                         float* __restrict__ sinT) {
    int idx = blockIdx.x * 256 + threadIdx.x; // SEQ*32
    int s = idx >> 5, i = idx & 31;
    float e = (2.0f * (float)i) / 64.0f;
    float theta = 1.0f / powf(1000000.0f, e);
    float ang = (float)s * theta;
    cosT[idx] = cosf(ang);
    sinT[idx] = sinf(ang);
}

// ---------------- MFMA GEMM core (m97-style), acc left in registers ----------------
__device__ __forceinline__ void gemm_core(const __bf16* __restrict__ A,
                                          const __bf16* __restrict__ Bt,
                                          int K, __bf16* As, __bf16* Bs,
                                          f32x4 (&acc)[4][4], int row0, int col0) {
    int tid = threadIdx.x;
    int w = tid >> 6, l = tid & 63, l15 = l & 15, g = l >> 4;
    int wr = (w >> 1) << 6, wc = (w & 1) << 6;

    int sr0 = tid >> 2;
    int sr1 = 64 + (tid >> 2);
    int lc0 = (((tid & 3) ^ ((tid >> 3) & 3)) << 3); // swizzled source chunk
    const __bf16* gA0 = A + (size_t)(row0 + sr0) * K + lc0;
    const __bf16* gA1 = A + (size_t)(row0 + sr1) * K + lc0;
    const __bf16* gB0 = Bt + (size_t)(col0 + sr0) * K + lc0;
    const __bf16* gB1 = Bt + (size_t)(col0 + sr1) * K + lc0;
    __bf16* lA0 = As + w * 512;
    __bf16* lA1 = As + 2048 + w * 512;
    __bf16* lB0 = Bs + w * 512;
    __bf16* lB1 = Bs + 2048 + w * 512;

    int rca = ((g ^ ((l15 >> 1) & 3)) << 3); // swizzled read chunk

#pragma unroll
    for (int i = 0; i < 4; ++i)
#pragma unroll
        for (int j = 0; j < 4; ++j) acc[i][j] = f4zero();

    for (int k0 = 0; k0 < K; k0 += 32) {
        __syncthreads();
        GLOAD_LDS16(gA0 + k0, lA0);
        GLOAD_LDS16(gA1 + k0, lA1);
        GLOAD_LDS16(gB0 + k0, lB0);
        GLOAD_LDS16(gB1 + k0, lB1);
        __syncthreads();

        bf16x8 af[4], bfr[4];
#pragma unroll
        for (int i = 0; i < 4; ++i) af[i] = *(const bf16x8*)&As[(wr + i * 16 + l15) * 32 + rca];
#pragma unroll
        for (int j = 0; j < 4; ++j) bfr[j] = *(const bf16x8*)&Bs[(wc + j * 16 + l15) * 32 + rca];
        __builtin_amdgcn_s_setprio(1);
#pragma unroll
        for (int i = 0; i < 4; ++i)
#pragma unroll
            for (int j = 0; j < 4; ++j)
                acc[i][j] = __builtin_amdgcn_mfma_f32_16x16x32_bf16(af[i], bfr[j], acc[i][j], 0, 0, 0);
        __builtin_amdgcn_s_setprio(0);
    }
}

// Fused QKV GEMM, 1D grid of 768 blocks:
//  bid <  512: Q/K (z = bid>>8) with RoPE epilogue, C row-major [row][DIM]
//  bid >= 512: V computed TRANSPOSED: vt[b*1024 + n][s] = sum_k wtv[n][k]*xn_b[s][k]
__global__ __launch_bounds__(256) void gemm_qkv_kernel(const __bf16* __restrict__ xn,
                                                       const __bf16* __restrict__ wq,
                                                       const __bf16* __restrict__ wk,
                                                       const __bf16* __restrict__ wv,
                                                       __bf16* __restrict__ qo,
                                                       __bf16* __restrict__ ko,
                                                       __bf16* __restrict__ vt,
                                                       const float* __restrict__ cosT,
                                                       const float* __restrict__ sinT) {
    __shared__ __bf16 As[128 * 32];
    __shared__ __bf16 Bs[128 * 32];
    int bid = blockIdx.x;
    int tid = threadIdx.x;
    int w = tid >> 6, l = tid & 63, l15 = l & 15, g = l >> 4;
    int wr = (w >> 1) << 6, wc = (w & 1) << 6;
    f32x4 acc[4][4];

    if (bid < 512) {
        int z = bid >> 8, t = bid & 255;
        int col0 = (t & 7) << 7, row0 = (t >> 3) << 7;
        gemm_core(xn, z ? wk : wq, DIM, As, Bs, acc, row0, col0);
        __bf16* C = z ? ko : qo;
        int colbase = col0 + wc;
#pragma unroll
        for (int i = 0; i < 4; ++i) {
#pragma unroll
            for (int r = 0; r < 4; ++r) {
                int row = row0 + wr + i * 16 + g * 4 + r;
                int s = row & (SEQ - 1);
#pragma unroll
                for (int j = 0; j < 2; ++j) {
                    float c = cosT[s * 32 + j * 16 + l15];
                    float sn = sinT[s * 32 + j * 16 + l15];
                    float x1 = acc[i][j][r], x2 = acc[i][j + 2][r];
                    C[(size_t)row * DIM + colbase + j * 16 + l15] = (__bf16)(x1 * c - x2 * sn);
                    C[(size_t)row * DIM + colbase + (j + 2) * 16 + l15] = (__bf16)(x1 * sn + x2 * c);
                }
            }
        }
    } else {
        int t = bid - 512;           // 256 blocks: [batch 2][n-blocks 8][s-blocks 16]
        int b = t >> 7, r7 = t & 127;
        int row0 = (r7 >> 4) << 7;   // n
        int col0 = (r7 & 15) << 7;   // s
        gemm_core(wv, xn + (size_t)b * SEQ * DIM, DIM, As, Bs, acc, row0, col0);
        __bf16* C = vt + (size_t)b * (NHEADS * HD) * SEQ;
#pragma unroll
        for (int i = 0; i < 4; ++i)
#pragma unroll
            for (int j = 0; j < 4; ++j)
#pragma unroll
                for (int r = 0; r < 4; ++r) {
                    int row = row0 + wr + i * 16 + g * 4 + r;
                    int col = col0 + wc + j * 16 + l15;
                    C[(size_t)row * SEQ + col] = (__bf16)acc[i][j][r];
                }
    }
}

__global__ __launch_bounds__(256) void gemm_out_kernel(const __bf16* __restrict__ ctx,
                                                       const __bf16* __restrict__ wo,
                                                       float* __restrict__ out) {
    __shared__ __bf16 As[128 * 32];
    __shared__ __bf16 Bs[128 * 32];
    int row0 = (int)blockIdx.y << 7, col0 = (int)blockIdx.x << 7;
    f32x4 acc[4][4];
    gemm_core(ctx, wo, DIM, As, Bs, acc, row0, col0);
    int tid = threadIdx.x;
    int w = tid >> 6, l = tid & 63, l15 = l & 15, g = l >> 4;
    int wr = (w >> 1) << 6, wc = (w & 1) << 6;
#pragma unroll
    for (int i = 0; i < 4; ++i)
#pragma unroll
        for (int j = 0; j < 4; ++j)
#pragma unroll
            for (int r = 0; r < 4; ++r) {
                int row = row0 + wr + i * 16 + g * 4 + r;
                int col = col0 + wc + j * 16 + l15;
                out[(size_t)row * DIM + col] = acc[i][j][r];
            }
}

// ---------------- Split-KV causal flash attention: 1 wave/block, NO LDS, NO barriers ----
// Grid (32 bh, 160 slots). Wave owns a 32-row q-strip; chunk = up to 16 KV tiles of 32.
// K/V loaded global->register directly in MFMA fragment layout (L2-resident).
// S^T = mfma(K,Q); in-lane softmax + shfl_xor(32); P via cvt_pk+permlane; O^T = mfma(V^T,P).
__global__ __launch_bounds__(64, 3) void attn_mfma_kernel(const __bf16* __restrict__ q,
                                                          const __bf16* __restrict__ k,
                                                          const __bf16* __restrict__ vt,
                                                          __bf16* __restrict__ part_O,
                                                          float* __restrict__ part_ml) {
    int bh = blockIdx.x;
    int slot = 159 - (int)blockIdx.y; // heavy chunks dispatch first
    int qp, ci;
    if (slot < 16) { qp = slot; ci = 0; }
    else if (slot < 48) { int t = slot - 16; qp = 16 + (t >> 1); ci = t & 1; }
    else if (slot < 96) { int t = slot - 48; qp = 32 + t / 3; ci = t - 3 * (t / 3); }
    else { int t = slot - 96; qp = 48 + (t >> 2); ci = t & 3; }
    int local = qp - (ci << 4);
    int ntiles = local < 16 ? local + 1 : 16;
    int dtile = local < 16 ? local : -1; // diagonal tile index within chunk (or none)
    int ks0 = ci << 9;                   // chunk KV start

    int b = bh >> 4, h = bh & 15;
    int l = threadIdx.x & 63;
    int l31 = l & 31, hi = l >> 5;
    size_t hoff = (size_t)(b * SEQ) * DIM + h * HD;
    const __bf16* vth = vt + (size_t)bh * HD * SEQ;
    int qrow = qp * 32 + l31;

    // Q B-frags, pre-scaled by 0.125*log2(e) -> QK^T lands in exp2 domain
    bf16x8 qf[4];
    {
        const __bf16* qptr = q + hoff + (size_t)qrow * DIM + hi * 8;
        const float c2 = 0.125f * 1.44269504f;
#pragma unroll
        for (int g = 0; g < 4; ++g) {
            bf16x8 t0 = *(const bf16x8*)(qptr + g * 16);
#pragma unroll
            for (int e = 0; e < 8; ++e) qf[g][e] = (__bf16)((float)t0[e] * c2);
        }
    }

    f32x16 oA, oB;
#pragma unroll
    for (int r = 0; r < 16; ++r) {
        oA[r] = 0.f;
        oB[r] = 0.f;
    }
    float m_run = -1e30f, l_run = 0.f;

    // direct-load pointers (fragment layout == lane layout)
    const __bf16* kptr = k + hoff + (size_t)(ks0 + l31) * DIM + hi * 8;
    const __bf16* vptr0 = vth + (size_t)l31 * SEQ + ks0 + hi * 8;
    const __bf16* vptr1 = vth + (size_t)(32 + l31) * SEQ + ks0 + hi * 8;

    bf16x8 ka[4], kb[4];
#pragma unroll
    for (int g = 0; g < 4; ++g) ka[g] = *(const bf16x8*)(kptr + g * 16);
    kptr += 32 * DIM;

    auto tile_body = [&](bf16x8 (&kcur)[4], bf16x8 (&knxt)[4], int st) {
        if (st + 1 < ntiles) { // prefetch next K tile
#pragma unroll
            for (int g = 0; g < 4; ++g) knxt[g] = *(const bf16x8*)(kptr + g * 16);
            kptr += 32 * DIM;
        }
        // V^T frags for this tile (consumed after softmax; latency hidden)
        bf16x8 vv0 = *(const bf16x8*)(vptr0);
        bf16x8 vv1 = *(const bf16x8*)(vptr0 + 16);
        bf16x8 vv2 = *(const bf16x8*)(vptr1);
        bf16x8 vv3 = *(const bf16x8*)(vptr1 + 16);
        vptr0 += 32;
        vptr1 += 32;

        // S^T = mfma(K, Q): rows = k-pos, cols = q (lane&31)
        f32x16 sa;
#pragma unroll
        for (int r = 0; r < 16; ++r) sa[r] = 0.f;
        __builtin_amdgcn_s_setprio(1);
#pragma unroll
        for (int g = 0; g < 4; ++g)
            sa = __builtin_amdgcn_mfma_f32_32x32x16_bf16(kcur[g], qf[g], sa, 0, 0, 0);
        __builtin_amdgcn_s_setprio(0);

        if (st == dtile) { // causal mask on the diagonal tile
            int s0 = ks0 + (st << 5);
#pragma unroll
            for (int r = 0; r < 16; ++r) {
                int kg = s0 + (r & 3) + 8 * (r >> 2) + 4 * hi;
                if (kg > qrow) sa[r] = -1e30f;
            }
        }

        // online softmax (exp2 domain), defer-max THR=10
        float lmax = sa[0];
#pragma unroll
        for (int r = 1; r < 16; ++r) lmax = fmaxf(lmax, sa[r]);
        if (!__all(lmax <= m_run + 10.0f)) {
            float omax = fmaxf(lmax, __shfl_xor(lmax, 32));
            float m_new = fmaxf(m_run, omax);
            float alpha = exp2f(m_run - m_new);
            l_run *= alpha;
#pragma unroll
            for (int r = 0; r < 16; ++r) {
                oA[r] *= alpha;
                oB[r] *= alpha;
            }
            m_run = m_new;
        }
        float ls = 0.f;
#pragma unroll
        for (int r = 0; r < 16; ++r) {
            sa[r] = exp2f(sa[r] - m_run);
            ls += sa[r];
        }
        l_run += ls + __shfl_xor(ls, 32);

        // pack P -> bf16 B-frags pa0 (k 0..15), pa1 (k 16..31)
        unsigned a0 = cvtpk(sa[0], sa[1]), b0 = cvtpk(sa[4], sa[5]);
        pl32swap(a0, b0);
        unsigned c0 = cvtpk(sa[2], sa[3]), d0 = cvtpk(sa[6], sa[7]);
        pl32swap(c0, d0);
        u32x4 t0 = {a0, c0, b0, d0};
        bf16x8 pa0 = __builtin_bit_cast(bf16x8, t0);
        unsigned a1 = cvtpk(sa[8], sa[9]), b1 = cvtpk(sa[12], sa[13]);
        pl32swap(a1, b1);
        unsigned c1 = cvtpk(sa[10], sa[11]), d1 = cvtpk(sa[14], sa[15]);
        pl32swap(c1, d1);
        u32x4 t1 = {a1, c1, b1, d1};
        bf16x8 pa1 = __builtin_bit_cast(bf16x8, t1);

        // O^T += mfma(V^T, P)
        __builtin_amdgcn_s_setprio(1);
        oA = __builtin_amdgcn_mfma_f32_32x32x16_bf16(vv0, pa0, oA, 0, 0, 0);
        oA = __builtin_amdgcn_mfma_f32_32x32x16_bf16(vv1, pa1, oA, 0, 0, 0);
        oB = __builtin_amdgcn_mfma_f32_32x32x16_bf16(vv2, pa0, oB, 0, 0, 0);
        oB = __builtin_amdgcn_mfma_f32_32x32x16_bf16(vv3, pa1, oB, 0, 0, 0);
        __builtin_amdgcn_s_setprio(0);
    };

    int st = 0;
    while (st < ntiles) {
        tile_body(ka, kb, st);
        ++st;
        if (st >= ntiles) break;
        tile_body(kb, ka, st);
        ++st;
    }

    // write unnormalized partial: O bf16 [slot][32 q][64 d], m/l f32 [slot][2][32]
    int gslot = bh * 160 + slot;
    __bf16* po = part_O + (size_t)gslot * 2048 + l31 * 64;
#pragma unroll
    for (int rr = 0; rr < 16; rr += 4) {
        int d0 = 8 * (rr >> 2) + 4 * hi;
        uint2 pA = {cvtpk(oA[rr], oA[rr + 1]), cvtpk(oA[rr + 2], oA[rr + 3])};
        uint2 pB = {cvtpk(oB[rr], oB[rr + 1]), cvtpk(oB[rr + 2], oB[rr + 3])};
        *(uint2*)&po[d0] = pA;
        *(uint2*)&po[32 + d0] = pB;
    }
    if (hi == 0) {
        part_ml[(size_t)gslot * 64 + l31] = m_run;
        part_ml[(size_t)gslot * 64 + 32 + l31] = l_run;
    }
}

// ---------------- Combine split-KV partials -> ctx ----------------
// Grid (32 bh, 64 strips), 128 threads: thread owns (row = t>>2, 16-d segment).
__global__ __launch_bounds__(128) void attn_combine_kernel(const __bf16* __restrict__ part_O,
                                                           const float* __restrict__ part_ml,
                                                           __bf16* __restrict__ ctx) {
    int bh = blockIdx.x, qp = blockIdx.y;
    int b = bh >> 4, h = bh & 15;
    int nch = (qp >> 4) + 1;
    int base = slot_base(qp);
    size_t so = (size_t)bh * 160 + base;
    int t = threadIdx.x;
    int row = t >> 2, dseg = (t & 3) << 4;

    float mv0 = -1e30f, mv1 = -1e30f, mv2 = -1e30f, mv3 = -1e30f;
    mv0 = part_ml[(so + 0) * 64 + row];
    if (nch > 1) mv1 = part_ml[(so + 1) * 64 + row];
    if (nch > 2) mv2 = part_ml[(so + 2) * 64 + row];
    if (nch > 3) mv3 = part_ml[(so + 3) * 64 + row];
    float mmax = fmaxf(fmaxf(mv0, mv1), fmaxf(mv2, mv3));

    float acc[16];
#pragma unroll
    for (int e = 0; e < 16; ++e) acc[e] = 0.f;
    float lsum = 0.f;

#pragma unroll 4
    for (int i = 0; i < 4; ++i) {
        if (i >= nch) break;
        float mi = i == 0 ? mv0 : i == 1 ? mv1 : i == 2 ? mv2 : mv3;
        float wsc = exp2f(mi - mmax);
        lsum += wsc * part_ml[(so + i) * 64 + 32 + row];
        const __bf16* po = part_O + (so + i) * 2048 + row * 64 + dseg;
        bf16x8 a = *(const bf16x8*)po;
        bf16x8 b2 = *(const bf16x8*)(po + 8);
#pragma unroll
        for (int e = 0; e < 8; ++e) {
            acc[e] += wsc * (float)a[e];
            acc[8 + e] += wsc * (float)b2[e];
        }
    }

    float inv = 1.0f / lsum;
    bf16x8 oa, ob;
#pragma unroll
    for (int e = 0; e < 8; ++e) {
        oa[e] = (__bf16)(acc[e] * inv);
        ob[e] = (__bf16)(acc[8 + e] * inv);
    }
    size_t off = ((size_t)(b * SEQ) + qp * 32 + row) * DIM + h * HD + dseg;
    *(bf16x8*)&ctx[off] = oa;
    *(bf16x8*)&ctx[off + 8] = ob;
}

extern "C" void kernel_launch(void* const* d_in, const int* in_sizes, int n_in,
                              void* d_out, int out_size, void* d_ws, size_t ws_size,
                              hipStream_t stream) {
    const float* x = (const float*)d_in[0];
    const float* w_norm = (const float*)d_in[1];
    const float* Wq = (const float*)d_in[2];
    const float* Wk = (const float*)d_in[3];
    const float* Wv = (const float*)d_in[4];
    const float* Wo = (const float*)d_in[5];
    float* out = (float*)d_out;
    char* w8 = (char*)d_ws;

    const size_t MB = 1ull << 20;
    // phase 1 region [0,14MB): xn + Wq/Wk/Wv transposed weights (dead after QKV GEMM)
    __bf16* xn = (__bf16*)(w8);               // [0,8)
    __bf16* wtq = (__bf16*)(w8 + 8 * MB);     // [8,10)
    __bf16* wtk = (__bf16*)(w8 + 10 * MB);    // [10,12)
    __bf16* wtv = (__bf16*)(w8 + 12 * MB);    // [12,14)
    // part_O reuses [0,20MB) during attention: 5120 slots * 4KB = 20MB
    __bf16* part_O = (__bf16*)(w8);
    __bf16* wto = (__bf16*)(w8 + 20 * MB);    // [20,22)
    __bf16* qb = (__bf16*)(w8 + 22 * MB);     // [22,30)
    __bf16* kb = (__bf16*)(w8 + 30 * MB);     // [30,38)
    __bf16* vtb = (__bf16*)(w8 + 38 * MB);    // [38,46)
    __bf16* ctx = (__bf16*)(w8 + 46 * MB);    // [46,54)
    float* cosT = (float*)(w8 + 54 * MB);     // 256KB
    float* sinT = cosT + SEQ * 32;            // 256KB -> ends 54.5MB
    float* part_ml = (float*)(w8 + 55 * MB);  // 5120*256B = 1.31MB

    wcvt_kernel<<<dim3(32, 32, 4), 256, 0, stream>>>(Wq, Wk, Wv, Wo, wtq, wtk, wtv, wto);
    rmsnorm_bf16<<<ROWS, 256, 0, stream>>>(x, w_norm, xn);
    rope_table_kernel<<<(SEQ * 32) / 256, 256, 0, stream>>>(cosT, sinT);

    gemm_qkv_kernel<<<768, 256, 0, stream>>>(xn, wtq, wtk, wtv, qb, kb, vtb, cosT, sinT);

    attn_mfma_kernel<<<dim3(BATCH * NHEADS, 160), 64, 0, stream>>>(qb, kb, vtb, part_O, part_ml);
    attn_combine_kernel<<<dim3(BATCH * NHEADS, SEQ / 32), 128, 0, stream>>>(part_O, part_ml, ctx);

    gemm_out_kernel<<<dim3(DIM / 128, ROWS / 128), 256, 0, stream>>>(ctx, wto, out);
}

// Round 9
// 144.368 us; speedup vs baseline: 1.1051x; 1.1051x over previous
//
#include <hip/hip_runtime.h>

#define DIM 1024
#define SEQ 2048
#define BATCH 2
#define NHEADS 16
#define HD 64
#define ROWS (BATCH * SEQ) // 4096

typedef __bf16 bf16x8 __attribute__((ext_vector_type(8)));
typedef __bf16 bf16x4 __attribute__((ext_vector_type(4)));
typedef float f32x4 __attribute__((ext_vector_type(4)));
typedef float f32x16 __attribute__((ext_vector_type(16)));
typedef unsigned u32x4 __attribute__((ext_vector_type(4)));

__device__ __forceinline__ f32x4 f4zero() {
    f32x4 z = {0.f, 0.f, 0.f, 0.f};
    return z;
}

__device__ __forceinline__ unsigned cvtpk(float lo, float hi) {
    unsigned r;
    asm("v_cvt_pk_bf16_f32 %0, %1, %2" : "=v"(r) : "v"(lo), "v"(hi));
    return r;
}

__device__ __forceinline__ void pl32swap(unsigned& a, unsigned& b) {
    asm volatile("v_permlane32_swap_b32 %0, %1" : "+v"(a), "+v"(b));
}

#define GLOAD_LDS16(g, l)                                                                  \
    __builtin_amdgcn_global_load_lds((const __attribute__((address_space(1))) void*)(g),   \
                                     (__attribute__((address_space(3))) void*)(l), 16, 0, 0)

// ---------------- RMSNorm -> bf16 ----------------
__global__ __launch_bounds__(256) void rmsnorm_bf16(const float* __restrict__ x,
                                                    const float* __restrict__ w,
                                                    __bf16* __restrict__ xn) {
    int row = blockIdx.x;
    int t = threadIdx.x;
    float4 v = ((const float4*)(x + (size_t)row * DIM))[t];
    float ss = v.x * v.x + v.y * v.y + v.z * v.z + v.w * v.w;
#pragma unroll
    for (int off = 1; off < 64; off <<= 1) ss += __shfl_xor(ss, off);
    __shared__ float red[4];
    if ((t & 63) == 0) red[t >> 6] = ss;
    __syncthreads();
    ss = red[0] + red[1] + red[2] + red[3];
    float scale = rsqrtf(ss * (1.0f / DIM) + 1e-5f);
    float4 wv = ((const float4*)w)[t];
    bf16x4 o;
    o[0] = (__bf16)(v.x * scale * wv.x);
    o[1] = (__bf16)(v.y * scale * wv.y);
    o[2] = (__bf16)(v.z * scale * wv.z);
    o[3] = (__bf16)(v.w * scale * wv.w);
    *(bf16x4*)(xn + (size_t)row * DIM + t * 4) = o;
}

// ---------------- Weight convert + transpose: W[k][n] f32 -> Wt[n][k] bf16 ----------------
__global__ __launch_bounds__(256) void wcvt_kernel(const float* __restrict__ Wq,
                                                   const float* __restrict__ Wk,
                                                   const float* __restrict__ Wv,
                                                   const float* __restrict__ Wo,
                                                   __bf16* tq, __bf16* tk, __bf16* tv, __bf16* to_) {
    int z = blockIdx.z;
    const float* W = z == 0 ? Wq : z == 1 ? Wk : z == 2 ? Wv : Wo;
    __bf16* T = z == 0 ? tq : z == 1 ? tk : z == 2 ? tv : to_;
    __shared__ float tile[32][33];
    int n0 = blockIdx.x * 32, k0 = blockIdx.y * 32;
    int tx = threadIdx.x & 31, ty = threadIdx.x >> 5;
#pragma unroll
    for (int j = 0; j < 32; j += 8) tile[ty + j][tx] = W[(size_t)(k0 + ty + j) * DIM + n0 + tx];
    __syncthreads();
#pragma unroll
    for (int j = 0; j < 32; j += 8)
        T[(size_t)(n0 + ty + j) * DIM + k0 + tx] = (__bf16)tile[tx][ty + j];
}

// ---------------- RoPE table ----------------
__global__ __launch_bounds__(256) void rope_table_kernel(float* __restrict__ cosT,
                                                         float* __restrict__ sinT) {
    int idx = blockIdx.x * 256 + threadIdx.x; // SEQ*32
    int s = idx >> 5, i = idx & 31;
    float e = (2.0f * (float)i) / 64.0f;
    float theta = 1.0f / powf(1000000.0f, e);
    float ang = (float)s * theta;
    cosT[idx] = cosf(ang);
    sinT[idx] = sinf(ang);
}

// ---------------- MFMA GEMM core (m97-style), acc left in registers ----------------
__device__ __forceinline__ void gemm_core(const __bf16* __restrict__ A,
                                          const __bf16* __restrict__ Bt,
                                          int K, __bf16* As, __bf16* Bs,
                                          f32x4 (&acc)[4][4], int row0, int col0) {
    int tid = threadIdx.x;
    int w = tid >> 6, l = tid & 63, l15 = l & 15, g = l >> 4;
    int wr = (w >> 1) << 6, wc = (w & 1) << 6;

    int sr0 = tid >> 2;
    int sr1 = 64 + (tid >> 2);
    int lc0 = (((tid & 3) ^ ((tid >> 3) & 3)) << 3); // swizzled source chunk
    const __bf16* gA0 = A + (size_t)(row0 + sr0) * K + lc0;
    const __bf16* gA1 = A + (size_t)(row0 + sr1) * K + lc0;
    const __bf16* gB0 = Bt + (size_t)(col0 + sr0) * K + lc0;
    const __bf16* gB1 = Bt + (size_t)(col0 + sr1) * K + lc0;
    __bf16* lA0 = As + w * 512;
    __bf16* lA1 = As + 2048 + w * 512;
    __bf16* lB0 = Bs + w * 512;
    __bf16* lB1 = Bs + 2048 + w * 512;

    int rca = ((g ^ ((l15 >> 1) & 3)) << 3); // swizzled read chunk

#pragma unroll
    for (int i = 0; i < 4; ++i)
#pragma unroll
        for (int j = 0; j < 4; ++j) acc[i][j] = f4zero();

    for (int k0 = 0; k0 < K; k0 += 32) {
        __syncthreads();
        GLOAD_LDS16(gA0 + k0, lA0);
        GLOAD_LDS16(gA1 + k0, lA1);
        GLOAD_LDS16(gB0 + k0, lB0);
        GLOAD_LDS16(gB1 + k0, lB1);
        __syncthreads();

        bf16x8 af[4], bfr[4];
#pragma unroll
        for (int i = 0; i < 4; ++i) af[i] = *(const bf16x8*)&As[(wr + i * 16 + l15) * 32 + rca];
#pragma unroll
        for (int j = 0; j < 4; ++j) bfr[j] = *(const bf16x8*)&Bs[(wc + j * 16 + l15) * 32 + rca];
        __builtin_amdgcn_s_setprio(1);
#pragma unroll
        for (int i = 0; i < 4; ++i)
#pragma unroll
            for (int j = 0; j < 4; ++j)
                acc[i][j] = __builtin_amdgcn_mfma_f32_16x16x32_bf16(af[i], bfr[j], acc[i][j], 0, 0, 0);
        __builtin_amdgcn_s_setprio(0);
    }
}

// Fused QKV GEMM, 1D grid of 768 blocks:
//  bid <  512: Q/K (z = bid>>8) with RoPE epilogue, C row-major [row][DIM]
//  bid >= 512: V computed TRANSPOSED: vt[b*1024 + n][s] = sum_k wtv[n][k]*xn_b[s][k]
__global__ __launch_bounds__(256) void gemm_qkv_kernel(const __bf16* __restrict__ xn,
                                                       const __bf16* __restrict__ wq,
                                                       const __bf16* __restrict__ wk,
                                                       const __bf16* __restrict__ wv,
                                                       __bf16* __restrict__ qo,
                                                       __bf16* __restrict__ ko,
                                                       __bf16* __restrict__ vt,
                                                       const float* __restrict__ cosT,
                                                       const float* __restrict__ sinT) {
    __shared__ __bf16 As[128 * 32];
    __shared__ __bf16 Bs[128 * 32];
    int bid = blockIdx.x;
    int tid = threadIdx.x;
    int w = tid >> 6, l = tid & 63, l15 = l & 15, g = l >> 4;
    int wr = (w >> 1) << 6, wc = (w & 1) << 6;
    f32x4 acc[4][4];

    if (bid < 512) {
        int z = bid >> 8, t = bid & 255;
        int col0 = (t & 7) << 7, row0 = (t >> 3) << 7;
        gemm_core(xn, z ? wk : wq, DIM, As, Bs, acc, row0, col0);
        __bf16* C = z ? ko : qo;
        int colbase = col0 + wc;
#pragma unroll
        for (int i = 0; i < 4; ++i) {
#pragma unroll
            for (int r = 0; r < 4; ++r) {
                int row = row0 + wr + i * 16 + g * 4 + r;
                int s = row & (SEQ - 1);
#pragma unroll
                for (int j = 0; j < 2; ++j) {
                    float c = cosT[s * 32 + j * 16 + l15];
                    float sn = sinT[s * 32 + j * 16 + l15];
                    float x1 = acc[i][j][r], x2 = acc[i][j + 2][r];
                    C[(size_t)row * DIM + colbase + j * 16 + l15] = (__bf16)(x1 * c - x2 * sn);
                    C[(size_t)row * DIM + colbase + (j + 2) * 16 + l15] = (__bf16)(x1 * sn + x2 * c);
                }
            }
        }
    } else {
        int t = bid - 512;           // 256 blocks: [batch 2][n-blocks 8][s-blocks 16]
        int b = t >> 7, r7 = t & 127;
        int row0 = (r7 >> 4) << 7;   // n
        int col0 = (r7 & 15) << 7;   // s
        gemm_core(wv, xn + (size_t)b * SEQ * DIM, DIM, As, Bs, acc, row0, col0);
        __bf16* C = vt + (size_t)b * (NHEADS * HD) * SEQ;
#pragma unroll
        for (int i = 0; i < 4; ++i)
#pragma unroll
            for (int j = 0; j < 4; ++j)
#pragma unroll
                for (int r = 0; r < 4; ++r) {
                    int row = row0 + wr + i * 16 + g * 4 + r;
                    int col = col0 + wc + j * 16 + l15;
                    C[(size_t)row * SEQ + col] = (__bf16)acc[i][j][r];
                }
    }
}

__global__ __launch_bounds__(256) void gemm_out_kernel(const __bf16* __restrict__ ctx,
                                                       const __bf16* __restrict__ wo,
                                                       float* __restrict__ out) {
    __shared__ __bf16 As[128 * 32];
    __shared__ __bf16 Bs[128 * 32];
    int row0 = (int)blockIdx.y << 7, col0 = (int)blockIdx.x << 7;
    f32x4 acc[4][4];
    gemm_core(ctx, wo, DIM, As, Bs, acc, row0, col0);
    int tid = threadIdx.x;
    int w = tid >> 6, l = tid & 63, l15 = l & 15, g = l >> 4;
    int wr = (w >> 1) << 6, wc = (w & 1) << 6;
#pragma unroll
    for (int i = 0; i < 4; ++i)
#pragma unroll
        for (int j = 0; j < 4; ++j)
#pragma unroll
            for (int r = 0; r < 4; ++r) {
                int row = row0 + wr + i * 16 + g * 4 + r;
                int col = col0 + wc + j * 16 + l15;
                out[(size_t)row * DIM + col] = acc[i][j][r];
            }
}

// ---------------- 8-wave causal flash attention (swapped-operand 32x32 MFMA) ----------------
// Block = 8 waves x 32 q-rows = 256 rows; grid (32 bh, 8 qb) = 256 blocks (1/CU).
// K/V double-buffered in LDS (36KB), ONE barrier per 64-KV tile, staging loads issued
// 2 tiles ahead (global->reg), LDS write just before the barrier (T14 async split).
// Per-wave math identical to the verified r7 kernel: S^T = mfma(K,Q); in-lane softmax
// + shfl_xor(32); P via cvt_pk+permlane32_swap; O^T = mfma(V^T,P); direct ctx write.
__global__ __launch_bounds__(512) void attn_fused_kernel(const __bf16* __restrict__ q,
                                                         const __bf16* __restrict__ k,
                                                         const __bf16* __restrict__ vt,
                                                         __bf16* __restrict__ ctx) {
    int bh = blockIdx.x;
    int qb = blockIdx.y;
    int b = bh >> 4, h = bh & 15;
    __shared__ __bf16 Ks[2][64][72]; // [buf][s_local][d]
    __shared__ __bf16 Vs[2][64][72]; // [buf][d][s_local]
    int tid = threadIdx.x, w = tid >> 6, l = tid & 63;
    int l31 = l & 31, hi = l >> 5;
    size_t hoff = (size_t)(b * SEQ) * DIM + h * HD;
    const __bf16* vth = vt + (size_t)bh * HD * SEQ;
    int qw0 = qb * 256 + w * 32;
    int qrow = qw0 + l31;
    int ntiles = 4 * qb + 4;              // tiles the block stages
    int mytiles = 4 * qb + (w >> 1) + 1;  // tiles this wave computes

    // Q B-frags, pre-scaled by 0.125*log2(e) -> QK^T lands in exp2 domain
    bf16x8 qf[4];
    {
        const __bf16* qptr = q + hoff + (size_t)qrow * DIM + hi * 8;
        const float c2 = 0.125f * 1.44269504f;
#pragma unroll
        for (int g = 0; g < 4; ++g) {
            bf16x8 t0 = *(const bf16x8*)(qptr + g * 16);
#pragma unroll
            for (int e = 0; e < 8; ++e) qf[g][e] = (__bf16)((float)t0[e] * c2);
        }
    }

    f32x16 oA, oB;
#pragma unroll
    for (int r = 0; r < 16; ++r) {
        oA[r] = 0.f;
        oB[r] = 0.f;
    }
    float m_run = -1e30f, l_run = 0.f;

    // staging: 512 threads cover one 64x64 K tile + one 64x64 V^T tile (one bf16x8 each)
    int srow = tid >> 3, scol = (tid & 7) * 8;
    const __bf16* kst = k + hoff + (size_t)srow * DIM + scol;
    const __bf16* vst = vth + (size_t)srow * SEQ + scol;

    // prologue: tile 0 -> LDS[0]; tile 1 -> regs (in flight across barrier)
    bf16x8 kr = *(const bf16x8*)kst;
    bf16x8 vr = *(const bf16x8*)vst;
    *(bf16x8*)&Ks[0][srow][scol] = kr;
    *(bf16x8*)&Vs[0][srow][scol] = vr;
    kr = *(const bf16x8*)(kst + (size_t)64 * DIM);
    vr = *(const bf16x8*)(vst + 64);
    __syncthreads();

    for (int st = 0; st < ntiles; ++st) {
        int cur = st & 1;
        // issue loads for tile st+2 (land during this tile's compute)
        bf16x8 kn, vn;
        if (st + 2 < ntiles) {
            kn = *(const bf16x8*)(kst + (size_t)((st + 2) * 64) * DIM);
            vn = *(const bf16x8*)(vst + (st + 2) * 64);
        }

        if (st < mytiles) { // wave-uniform branch
            int s0 = st << 6;
            // S^T = mfma(K, Q): sa = k-rows 0..31, sb = 32..63 (cols = q = lane&31)
            f32x16 sa, sb;
#pragma unroll
            for (int r = 0; r < 16; ++r) {
                sa[r] = 0.f;
                sb[r] = 0.f;
            }
            __builtin_amdgcn_s_setprio(1);
#pragma unroll
            for (int g = 0; g < 4; ++g) {
                bf16x8 ka = *(const bf16x8*)&Ks[cur][l31][g * 16 + hi * 8];
                bf16x8 kb2 = *(const bf16x8*)&Ks[cur][32 + l31][g * 16 + hi * 8];
                sa = __builtin_amdgcn_mfma_f32_32x32x16_bf16(ka, qf[g], sa, 0, 0, 0);
                sb = __builtin_amdgcn_mfma_f32_32x32x16_bf16(kb2, qf[g], sb, 0, 0, 0);
            }
            __builtin_amdgcn_s_setprio(0);

            if (s0 + 63 > qw0) { // causal mask (diagonal region only)
#pragma unroll
                for (int r = 0; r < 16; ++r) {
                    int kg = s0 + (r & 3) + 8 * (r >> 2) + 4 * hi;
                    if (kg > qrow) sa[r] = -1e30f;
                    if (kg + 32 > qrow) sb[r] = -1e30f;
                }
            }

            // online softmax (exp2 domain), defer-max THR=10
            float lmax = -3e38f;
#pragma unroll
            for (int r = 0; r < 16; ++r) lmax = fmaxf(lmax, fmaxf(sa[r], sb[r]));
            if (!__all(lmax <= m_run + 10.0f)) {
                float omax = fmaxf(lmax, __shfl_xor(lmax, 32));
                float m_new = fmaxf(m_run, omax);
                float alpha = exp2f(m_run - m_new);
                l_run *= alpha;
#pragma unroll
                for (int r = 0; r < 16; ++r) {
                    oA[r] *= alpha;
                    oB[r] *= alpha;
                }
                m_run = m_new;
            }
            float ls = 0.f;
#pragma unroll
            for (int r = 0; r < 16; ++r) {
                sa[r] = exp2f(sa[r] - m_run);
                ls += sa[r];
                sb[r] = exp2f(sb[r] - m_run);
                ls += sb[r];
            }
            l_run += ls + __shfl_xor(ls, 32);

            // pack P -> bf16 B-frags: pa[ks] = P[q=lane&31][ks*16 + hi*8 + 0..7]
            bf16x8 pa[4];
#pragma unroll
            for (int g = 0; g < 2; ++g) {
                unsigned a_ = cvtpk(sa[8 * g + 0], sa[8 * g + 1]);
                unsigned b_ = cvtpk(sa[8 * g + 4], sa[8 * g + 5]);
                pl32swap(a_, b_);
                unsigned c_ = cvtpk(sa[8 * g + 2], sa[8 * g + 3]);
                unsigned d_ = cvtpk(sa[8 * g + 6], sa[8 * g + 7]);
                pl32swap(c_, d_);
                u32x4 t4 = {a_, c_, b_, d_};
                pa[g] = __builtin_bit_cast(bf16x8, t4);
            }
#pragma unroll
            for (int g = 0; g < 2; ++g) {
                unsigned a_ = cvtpk(sb[8 * g + 0], sb[8 * g + 1]);
                unsigned b_ = cvtpk(sb[8 * g + 4], sb[8 * g + 5]);
                pl32swap(a_, b_);
                unsigned c_ = cvtpk(sb[8 * g + 2], sb[8 * g + 3]);
                unsigned d_ = cvtpk(sb[8 * g + 6], sb[8 * g + 7]);
                pl32swap(c_, d_);
                u32x4 t4 = {a_, c_, b_, d_};
                pa[2 + g] = __builtin_bit_cast(bf16x8, t4);
            }

            // O^T += mfma(V^T, P): oA = d 0..31, oB = d 32..63
            __builtin_amdgcn_s_setprio(1);
#pragma unroll
            for (int ks = 0; ks < 4; ++ks) {
                bf16x8 va = *(const bf16x8*)&Vs[cur][l31][ks * 16 + hi * 8];
                bf16x8 vb2 = *(const bf16x8*)&Vs[cur][32 + l31][ks * 16 + hi * 8];
                oA = __builtin_amdgcn_mfma_f32_32x32x16_bf16(va, pa[ks], oA, 0, 0, 0);
                oB = __builtin_amdgcn_mfma_f32_32x32x16_bf16(vb2, pa[ks], oB, 0, 0, 0);
            }
            __builtin_amdgcn_s_setprio(0);
        }

        // write tile st+1 (loaded last iteration, vmcnt already landed) into the
        // buffer whose readers finished at the previous barrier
        if (st + 1 < ntiles) {
            *(bf16x8*)&Ks[cur ^ 1][srow][scol] = kr;
            *(bf16x8*)&Vs[cur ^ 1][srow][scol] = vr;
            kr = kn;
            vr = vn;
        }
        __syncthreads();
    }

    float inv = 1.0f / l_run;
#pragma unroll
    for (int rr = 0; rr < 16; rr += 4) {
        int d = 8 * (rr >> 2) + 4 * hi; // contiguous d..d+3
        uint2 pA = {cvtpk(oA[rr] * inv, oA[rr + 1] * inv), cvtpk(oA[rr + 2] * inv, oA[rr + 3] * inv)};
        uint2 pB = {cvtpk(oB[rr] * inv, oB[rr + 1] * inv), cvtpk(oB[rr + 2] * inv, oB[rr + 3] * inv)};
        *(uint2*)&ctx[hoff + (size_t)qrow * DIM + d] = pA;
        *(uint2*)&ctx[hoff + (size_t)qrow * DIM + 32 + d] = pB;
    }
}

extern "C" void kernel_launch(void* const* d_in, const int* in_sizes, int n_in,
                              void* d_out, int out_size, void* d_ws, size_t ws_size,
                              hipStream_t stream) {
    const float* x = (const float*)d_in[0];
    const float* w_norm = (const float*)d_in[1];
    const float* Wq = (const float*)d_in[2];
    const float* Wk = (const float*)d_in[3];
    const float* Wv = (const float*)d_in[4];
    const float* Wo = (const float*)d_in[5];
    float* out = (float*)d_out;
    char* w8 = (char*)d_ws;

    const size_t MB = 1ull << 20;
    __bf16* xn = (__bf16*)(w8);               // [0,8)
    __bf16* wtq = (__bf16*)(w8 + 8 * MB);     // [8,10)
    __bf16* wtk = (__bf16*)(w8 + 10 * MB);    // [10,12)
    __bf16* wtv = (__bf16*)(w8 + 12 * MB);    // [12,14)
    __bf16* wto = (__bf16*)(w8 + 14 * MB);    // [14,16)
    __bf16* qb = (__bf16*)(w8 + 16 * MB);     // [16,24)
    __bf16* kb = (__bf16*)(w8 + 24 * MB);     // [24,32)
    __bf16* vtb = (__bf16*)(w8 + 32 * MB);    // [32,40)
    __bf16* ctx = (__bf16*)(w8 + 40 * MB);    // [40,48)
    float* cosT = (float*)(w8 + 48 * MB);     // 256KB
    float* sinT = cosT + SEQ * 32;            // 256KB

    wcvt_kernel<<<dim3(32, 32, 4), 256, 0, stream>>>(Wq, Wk, Wv, Wo, wtq, wtk, wtv, wto);
    rmsnorm_bf16<<<ROWS, 256, 0, stream>>>(x, w_norm, xn);
    rope_table_kernel<<<(SEQ * 32) / 256, 256, 0, stream>>>(cosT, sinT);

    gemm_qkv_kernel<<<768, 256, 0, stream>>>(xn, wtq, wtk, wtv, qb, kb, vtb, cosT, sinT);

    attn_fused_kernel<<<dim3(BATCH * NHEADS, SEQ / 256), 512, 0, stream>>>(qb, kb, vtb, ctx);

    gemm_out_kernel<<<dim3(DIM / 128, ROWS / 128), 256, 0, stream>>>(ctx, wto, out);
}

// Round 10
// 140.077 us; speedup vs baseline: 1.1390x; 1.0306x over previous
//
#include <hip/hip_runtime.h>

#define DIM 1024
#define SEQ 2048
#define BATCH 2
#define NHEADS 16
#define HD 64
#define ROWS (BATCH * SEQ) // 4096

typedef __bf16 bf16x8 __attribute__((ext_vector_type(8)));
typedef __bf16 bf16x4 __attribute__((ext_vector_type(4)));
typedef float f32x4 __attribute__((ext_vector_type(4)));
typedef float f32x16 __attribute__((ext_vector_type(16)));
typedef unsigned u32x4 __attribute__((ext_vector_type(4)));

__device__ __forceinline__ f32x4 f4zero() {
    f32x4 z = {0.f, 0.f, 0.f, 0.f};
    return z;
}

__device__ __forceinline__ unsigned cvtpk(float lo, float hi) {
    unsigned r;
    asm("v_cvt_pk_bf16_f32 %0, %1, %2" : "=v"(r) : "v"(lo), "v"(hi));
    return r;
}

__device__ __forceinline__ void pl32swap(unsigned& a, unsigned& b) {
    asm volatile("v_permlane32_swap_b32 %0, %1" : "+v"(a), "+v"(b));
}

#define GLOAD_LDS16(g, l)                                                                  \
    __builtin_amdgcn_global_load_lds((const __attribute__((address_space(1))) void*)(g),   \
                                     (__attribute__((address_space(3))) void*)(l), 16, 0, 0)

// ---------------- RMSNorm -> bf16 ----------------
__global__ __launch_bounds__(256) void rmsnorm_bf16(const float* __restrict__ x,
                                                    const float* __restrict__ w,
                                                    __bf16* __restrict__ xn) {
    int row = blockIdx.x;
    int t = threadIdx.x;
    float4 v = ((const float4*)(x + (size_t)row * DIM))[t];
    float ss = v.x * v.x + v.y * v.y + v.z * v.z + v.w * v.w;
#pragma unroll
    for (int off = 1; off < 64; off <<= 1) ss += __shfl_xor(ss, off);
    __shared__ float red[4];
    if ((t & 63) == 0) red[t >> 6] = ss;
    __syncthreads();
    ss = red[0] + red[1] + red[2] + red[3];
    float scale = rsqrtf(ss * (1.0f / DIM) + 1e-5f);
    float4 wv = ((const float4*)w)[t];
    bf16x4 o;
    o[0] = (__bf16)(v.x * scale * wv.x);
    o[1] = (__bf16)(v.y * scale * wv.y);
    o[2] = (__bf16)(v.z * scale * wv.z);
    o[3] = (__bf16)(v.w * scale * wv.w);
    *(bf16x4*)(xn + (size_t)row * DIM + t * 4) = o;
}

// ---------------- Weight convert + transpose: W[k][n] f32 -> Wt[n][k] bf16 ----------------
__global__ __launch_bounds__(256) void wcvt_kernel(const float* __restrict__ Wq,
                                                   const float* __restrict__ Wk,
                                                   const float* __restrict__ Wv,
                                                   const float* __restrict__ Wo,
                                                   __bf16* tq, __bf16* tk, __bf16* tv, __bf16* to_) {
    int z = blockIdx.z;
    const float* W = z == 0 ? Wq : z == 1 ? Wk : z == 2 ? Wv : Wo;
    __bf16* T = z == 0 ? tq : z == 1 ? tk : z == 2 ? tv : to_;
    __shared__ float tile[32][33];
    int n0 = blockIdx.x * 32, k0 = blockIdx.y * 32;
    int tx = threadIdx.x & 31, ty = threadIdx.x >> 5;
#pragma unroll
    for (int j = 0; j < 32; j += 8) tile[ty + j][tx] = W[(size_t)(k0 + ty + j) * DIM + n0 + tx];
    __syncthreads();
#pragma unroll
    for (int j = 0; j < 32; j += 8)
        T[(size_t)(n0 + ty + j) * DIM + k0 + tx] = (__bf16)tile[tx][ty + j];
}

// ---------------- RoPE table ----------------
__global__ __launch_bounds__(256) void rope_table_kernel(float* __restrict__ cosT,
                                                         float* __restrict__ sinT) {
    int idx = blockIdx.x * 256 + threadIdx.x; // SEQ*32
    int s = idx >> 5, i = idx & 31;
    float e = (2.0f * (float)i) / 64.0f;
    float theta = 1.0f / powf(1000000.0f, e);
    float ang = (float)s * theta;
    cosT[idx] = cosf(ang);
    sinT[idx] = sinf(ang);
}

// ---------------- MFMA GEMM core (m97-style), acc left in registers ----------------
__device__ __forceinline__ void gemm_core(const __bf16* __restrict__ A,
                                          const __bf16* __restrict__ Bt,
                                          int K, __bf16* As, __bf16* Bs,
                                          f32x4 (&acc)[4][4], int row0, int col0) {
    int tid = threadIdx.x;
    int w = tid >> 6, l = tid & 63, l15 = l & 15, g = l >> 4;
    int wr = (w >> 1) << 6, wc = (w & 1) << 6;

    int sr0 = tid >> 2;
    int sr1 = 64 + (tid >> 2);
    int lc0 = (((tid & 3) ^ ((tid >> 3) & 3)) << 3); // swizzled source chunk
    const __bf16* gA0 = A + (size_t)(row0 + sr0) * K + lc0;
    const __bf16* gA1 = A + (size_t)(row0 + sr1) * K + lc0;
    const __bf16* gB0 = Bt + (size_t)(col0 + sr0) * K + lc0;
    const __bf16* gB1 = Bt + (size_t)(col0 + sr1) * K + lc0;
    __bf16* lA0 = As + w * 512;
    __bf16* lA1 = As + 2048 + w * 512;
    __bf16* lB0 = Bs + w * 512;
    __bf16* lB1 = Bs + 2048 + w * 512;

    int rca = ((g ^ ((l15 >> 1) & 3)) << 3); // swizzled read chunk

#pragma unroll
    for (int i = 0; i < 4; ++i)
#pragma unroll
        for (int j = 0; j < 4; ++j) acc[i][j] = f4zero();

    for (int k0 = 0; k0 < K; k0 += 32) {
        __syncthreads();
        GLOAD_LDS16(gA0 + k0, lA0);
        GLOAD_LDS16(gA1 + k0, lA1);
        GLOAD_LDS16(gB0 + k0, lB0);
        GLOAD_LDS16(gB1 + k0, lB1);
        __syncthreads();

        bf16x8 af[4], bfr[4];
#pragma unroll
        for (int i = 0; i < 4; ++i) af[i] = *(const bf16x8*)&As[(wr + i * 16 + l15) * 32 + rca];
#pragma unroll
        for (int j = 0; j < 4; ++j) bfr[j] = *(const bf16x8*)&Bs[(wc + j * 16 + l15) * 32 + rca];
        __builtin_amdgcn_s_setprio(1);
#pragma unroll
        for (int i = 0; i < 4; ++i)
#pragma unroll
            for (int j = 0; j < 4; ++j)
                acc[i][j] = __builtin_amdgcn_mfma_f32_16x16x32_bf16(af[i], bfr[j], acc[i][j], 0, 0, 0);
        __builtin_amdgcn_s_setprio(0);
    }
}

// Fused QKV GEMM, 1D grid of 768 blocks:
//  bid <  512: Q/K (z = bid>>8) with RoPE epilogue, C row-major [row][DIM]
//  bid >= 512: V computed TRANSPOSED: vt[b*1024 + n][s] = sum_k wtv[n][k]*xn_b[s][k]
__global__ __launch_bounds__(256) void gemm_qkv_kernel(const __bf16* __restrict__ xn,
                                                       const __bf16* __restrict__ wq,
                                                       const __bf16* __restrict__ wk,
                                                       const __bf16* __restrict__ wv,
                                                       __bf16* __restrict__ qo,
                                                       __bf16* __restrict__ ko,
                                                       __bf16* __restrict__ vt,
                                                       const float* __restrict__ cosT,
                                                       const float* __restrict__ sinT) {
    __shared__ __bf16 As[128 * 32];
    __shared__ __bf16 Bs[128 * 32];
    int bid = blockIdx.x;
    int tid = threadIdx.x;
    int w = tid >> 6, l = tid & 63, l15 = l & 15, g = l >> 4;
    int wr = (w >> 1) << 6, wc = (w & 1) << 6;
    f32x4 acc[4][4];

    if (bid < 512) {
        int z = bid >> 8, t = bid & 255;
        int col0 = (t & 7) << 7, row0 = (t >> 3) << 7;
        gemm_core(xn, z ? wk : wq, DIM, As, Bs, acc, row0, col0);
        __bf16* C = z ? ko : qo;
        int colbase = col0 + wc;
#pragma unroll
        for (int i = 0; i < 4; ++i) {
#pragma unroll
            for (int r = 0; r < 4; ++r) {
                int row = row0 + wr + i * 16 + g * 4 + r;
                int s = row & (SEQ - 1);
#pragma unroll
                for (int j = 0; j < 2; ++j) {
                    float c = cosT[s * 32 + j * 16 + l15];
                    float sn = sinT[s * 32 + j * 16 + l15];
                    float x1 = acc[i][j][r], x2 = acc[i][j + 2][r];
                    C[(size_t)row * DIM + colbase + j * 16 + l15] = (__bf16)(x1 * c - x2 * sn);
                    C[(size_t)row * DIM + colbase + (j + 2) * 16 + l15] = (__bf16)(x1 * sn + x2 * c);
                }
            }
        }
    } else {
        int t = bid - 512;           // 256 blocks: [batch 2][n-blocks 8][s-blocks 16]
        int b = t >> 7, r7 = t & 127;
        int row0 = (r7 >> 4) << 7;   // n
        int col0 = (r7 & 15) << 7;   // s
        gemm_core(wv, xn + (size_t)b * SEQ * DIM, DIM, As, Bs, acc, row0, col0);
        __bf16* C = vt + (size_t)b * (NHEADS * HD) * SEQ;
#pragma unroll
        for (int i = 0; i < 4; ++i)
#pragma unroll
            for (int j = 0; j < 4; ++j)
#pragma unroll
                for (int r = 0; r < 4; ++r) {
                    int row = row0 + wr + i * 16 + g * 4 + r;
                    int col = col0 + wc + j * 16 + l15;
                    C[(size_t)row * SEQ + col] = (__bf16)acc[i][j][r];
                }
    }
}

__global__ __launch_bounds__(256) void gemm_out_kernel(const __bf16* __restrict__ ctx,
                                                       const __bf16* __restrict__ wo,
                                                       float* __restrict__ out) {
    __shared__ __bf16 As[128 * 32];
    __shared__ __bf16 Bs[128 * 32];
    int row0 = (int)blockIdx.y << 7, col0 = (int)blockIdx.x << 7;
    f32x4 acc[4][4];
    gemm_core(ctx, wo, DIM, As, Bs, acc, row0, col0);
    int tid = threadIdx.x;
    int w = tid >> 6, l = tid & 63, l15 = l & 15, g = l >> 4;
    int wr = (w >> 1) << 6, wc = (w & 1) << 6;
#pragma unroll
    for (int i = 0; i < 4; ++i)
#pragma unroll
        for (int j = 0; j < 4; ++j)
#pragma unroll
            for (int r = 0; r < 4; ++r) {
                int row = row0 + wr + i * 16 + g * 4 + r;
                int col = col0 + wc + j * 16 + l15;
                out[(size_t)row * DIM + col] = acc[i][j][r];
            }
}

// ---------------- Strip-interleaved causal flash attention ----------------
// Block = 4 waves; wave w owns q-strip sidx = j + 16w (32 rows). Grid (32 bh, 16 j)
// = 512 blocks, 2/CU; per-block staged tiles 25..32 and compute ~equal -> no tail.
// K/V double-buffered LDS; RAW barrier (lgkmcnt(0) + s_barrier) so the global
// prefetch (issued 2 tiles ahead) floats across barriers (counted vmcnt at use).
// Math identical to verified r7/r9: S^T=mfma(K,Q), in-lane softmax, cvt_pk+permlane,
// O^T=mfma(V^T,P).
__global__ __launch_bounds__(256, 2) void attn_fused_kernel(const __bf16* __restrict__ q,
                                                            const __bf16* __restrict__ k,
                                                            const __bf16* __restrict__ vt,
                                                            __bf16* __restrict__ ctx) {
    int bh = blockIdx.x;
    int j = 15 - (int)blockIdx.y; // heavier j first
    int b = bh >> 4, h = bh & 15;
    __shared__ __bf16 Ks[2][64][72]; // [buf][s_local][d]
    __shared__ __bf16 Vs[2][64][72]; // [buf][d][s_local]
    int tid = threadIdx.x, w = tid >> 6, l = tid & 63;
    int l31 = l & 31, hi = l >> 5;
    size_t hoff = (size_t)(b * SEQ) * DIM + h * HD;
    const __bf16* vth = vt + (size_t)bh * HD * SEQ;
    int sidx = j + 16 * w;              // q-strip index (0..63)
    int qw0 = sidx * 32;
    int qrow = qw0 + l31;
    int mytiles = (sidx >> 1) + 1;      // tiles this wave computes
    int ntiles = ((j + 48) >> 1) + 1;   // tiles the block stages (wave 3's need)

    // Q B-frags, pre-scaled by 0.125*log2(e) -> QK^T lands in exp2 domain
    bf16x8 qf[4];
    {
        const __bf16* qptr = q + hoff + (size_t)qrow * DIM + hi * 8;
        const float c2 = 0.125f * 1.44269504f;
#pragma unroll
        for (int g = 0; g < 4; ++g) {
            bf16x8 t0 = *(const bf16x8*)(qptr + g * 16);
#pragma unroll
            for (int e = 0; e < 8; ++e) qf[g][e] = (__bf16)((float)t0[e] * c2);
        }
    }

    f32x16 oA, oB;
#pragma unroll
    for (int r = 0; r < 16; ++r) {
        oA[r] = 0.f;
        oB[r] = 0.f;
    }
    float m_run = -1e30f, l_run = 0.f;

    // staging: 256 threads; K rows sr,sr+32 / V^T rows sr,sr+32 (one bf16x8 each)
    int sr = tid >> 3, sc = (tid & 7) * 8;
    const __bf16* kst = k + hoff + (size_t)sr * DIM + sc;
    const __bf16* vst = vth + (size_t)sr * SEQ + sc;

    // prologue: tile 0 -> LDS[0]; tile 1 -> regs (stays in flight across barriers)
    bf16x8 kr0 = *(const bf16x8*)kst;
    bf16x8 kr1 = *(const bf16x8*)(kst + (size_t)32 * DIM);
    bf16x8 vr0 = *(const bf16x8*)vst;
    bf16x8 vr1 = *(const bf16x8*)(vst + (size_t)32 * SEQ);
    *(bf16x8*)&Ks[0][sr][sc] = kr0;
    *(bf16x8*)&Ks[0][32 + sr][sc] = kr1;
    *(bf16x8*)&Vs[0][sr][sc] = vr0;
    *(bf16x8*)&Vs[0][32 + sr][sc] = vr1;
    kr0 = *(const bf16x8*)(kst + (size_t)64 * DIM);
    kr1 = *(const bf16x8*)(kst + (size_t)96 * DIM);
    vr0 = *(const bf16x8*)(vst + 64);
    vr1 = *(const bf16x8*)(vst + (size_t)32 * SEQ + 64);
    asm volatile("s_waitcnt lgkmcnt(0)" ::: "memory");
    __builtin_amdgcn_s_barrier();
    __builtin_amdgcn_sched_barrier(0);

    for (int st = 0; st < ntiles; ++st) {
        int cur = st & 1;
        // issue loads for tile st+2 (consumed as LDS-write next iteration)
        bf16x8 kn0, kn1, vn0, vn1;
        if (st + 2 < ntiles) {
            size_t ko = (size_t)((st + 2) * 64) * DIM;
            kn0 = *(const bf16x8*)(kst + ko);
            kn1 = *(const bf16x8*)(kst + ko + (size_t)32 * DIM);
            vn0 = *(const bf16x8*)(vst + (st + 2) * 64);
            vn1 = *(const bf16x8*)(vst + (size_t)32 * SEQ + (st + 2) * 64);
        }

        if (st < mytiles) { // wave-uniform
            int s0 = st << 6;
            f32x16 sa, sb;
#pragma unroll
            for (int r = 0; r < 16; ++r) {
                sa[r] = 0.f;
                sb[r] = 0.f;
            }
            __builtin_amdgcn_s_setprio(1);
#pragma unroll
            for (int g = 0; g < 4; ++g) {
                bf16x8 ka = *(const bf16x8*)&Ks[cur][l31][g * 16 + hi * 8];
                bf16x8 kb2 = *(const bf16x8*)&Ks[cur][32 + l31][g * 16 + hi * 8];
                sa = __builtin_amdgcn_mfma_f32_32x32x16_bf16(ka, qf[g], sa, 0, 0, 0);
                sb = __builtin_amdgcn_mfma_f32_32x32x16_bf16(kb2, qf[g], sb, 0, 0, 0);
            }
            __builtin_amdgcn_s_setprio(0);

            if (s0 + 63 > qw0) { // causal mask (diagonal region only)
#pragma unroll
                for (int r = 0; r < 16; ++r) {
                    int kg = s0 + (r & 3) + 8 * (r >> 2) + 4 * hi;
                    if (kg > qrow) sa[r] = -1e30f;
                    if (kg + 32 > qrow) sb[r] = -1e30f;
                }
            }

            // online softmax (exp2 domain), defer-max THR=10; tree reductions
            float mx[8];
#pragma unroll
            for (int r = 0; r < 8; ++r) mx[r] = fmaxf(sa[r], sa[r + 8]);
#pragma unroll
            for (int r = 0; r < 8; ++r) mx[r] = fmaxf(mx[r], fmaxf(sb[r], sb[r + 8]));
#pragma unroll
            for (int r = 0; r < 4; ++r) mx[r] = fmaxf(mx[r], mx[r + 4]);
            float lmax = fmaxf(fmaxf(mx[0], mx[1]), fmaxf(mx[2], mx[3]));
            if (!__all(lmax <= m_run + 10.0f)) {
                float omax = fmaxf(lmax, __shfl_xor(lmax, 32));
                float m_new = fmaxf(m_run, omax);
                float alpha = exp2f(m_run - m_new);
                l_run *= alpha;
#pragma unroll
                for (int r = 0; r < 16; ++r) {
                    oA[r] *= alpha;
                    oB[r] *= alpha;
                }
                m_run = m_new;
            }
            float s4[8];
#pragma unroll
            for (int r = 0; r < 16; ++r) {
                sa[r] = exp2f(sa[r] - m_run);
                sb[r] = exp2f(sb[r] - m_run);
            }
#pragma unroll
            for (int r = 0; r < 8; ++r) s4[r] = (sa[r] + sa[r + 8]) + (sb[r] + sb[r + 8]);
#pragma unroll
            for (int r = 0; r < 4; ++r) s4[r] += s4[r + 4];
            float ls = (s4[0] + s4[1]) + (s4[2] + s4[3]);
            l_run += ls + __shfl_xor(ls, 32);

            // pack P -> bf16 B-frags: pa[ks] = P[q=lane&31][ks*16 + hi*8 + 0..7]
            bf16x8 pa[4];
#pragma unroll
            for (int g = 0; g < 2; ++g) {
                unsigned a_ = cvtpk(sa[8 * g + 0], sa[8 * g + 1]);
                unsigned b_ = cvtpk(sa[8 * g + 4], sa[8 * g + 5]);
                pl32swap(a_, b_);
                unsigned c_ = cvtpk(sa[8 * g + 2], sa[8 * g + 3]);
                unsigned d_ = cvtpk(sa[8 * g + 6], sa[8 * g + 7]);
                pl32swap(c_, d_);
                u32x4 t4 = {a_, c_, b_, d_};
                pa[g] = __builtin_bit_cast(bf16x8, t4);
            }
#pragma unroll
            for (int g = 0; g < 2; ++g) {
                unsigned a_ = cvtpk(sb[8 * g + 0], sb[8 * g + 1]);
                unsigned b_ = cvtpk(sb[8 * g + 4], sb[8 * g + 5]);
                pl32swap(a_, b_);
                unsigned c_ = cvtpk(sb[8 * g + 2], sb[8 * g + 3]);
                unsigned d_ = cvtpk(sb[8 * g + 6], sb[8 * g + 7]);
                pl32swap(c_, d_);
                u32x4 t4 = {a_, c_, b_, d_};
                pa[2 + g] = __builtin_bit_cast(bf16x8, t4);
            }

            // O^T += mfma(V^T, P): oA = d 0..31, oB = d 32..63
            __builtin_amdgcn_s_setprio(1);
#pragma unroll
            for (int ks = 0; ks < 4; ++ks) {
                bf16x8 va = *(const bf16x8*)&Vs[cur][l31][ks * 16 + hi * 8];
                bf16x8 vb2 = *(const bf16x8*)&Vs[cur][32 + l31][ks * 16 + hi * 8];
                oA = __builtin_amdgcn_mfma_f32_32x32x16_bf16(va, pa[ks], oA, 0, 0, 0);
                oB = __builtin_amdgcn_mfma_f32_32x32x16_bf16(vb2, pa[ks], oB, 0, 0, 0);
            }
            __builtin_amdgcn_s_setprio(0);
        }

        // write tile st+1 (loaded last iteration) into the idle buffer, swap regs
        if (st + 1 < ntiles) {
            *(bf16x8*)&Ks[cur ^ 1][sr][sc] = kr0;
            *(bf16x8*)&Ks[cur ^ 1][32 + sr][sc] = kr1;
            *(bf16x8*)&Vs[cur ^ 1][sr][sc] = vr0;
            *(bf16x8*)&Vs[cur ^ 1][32 + sr][sc] = vr1;
            kr0 = kn0;
            kr1 = kn1;
            vr0 = vn0;
            vr1 = vn1;
            asm volatile("s_waitcnt lgkmcnt(0)" ::: "memory");
            __builtin_amdgcn_s_barrier();
            __builtin_amdgcn_sched_barrier(0);
        }
    }

    float inv = 1.0f / l_run;
#pragma unroll
    for (int rr = 0; rr < 16; rr += 4) {
        int d = 8 * (rr >> 2) + 4 * hi; // contiguous d..d+3
        uint2 pA = {cvtpk(oA[rr] * inv, oA[rr + 1] * inv), cvtpk(oA[rr + 2] * inv, oA[rr + 3] * inv)};
        uint2 pB = {cvtpk(oB[rr] * inv, oB[rr + 1] * inv), cvtpk(oB[rr + 2] * inv, oB[rr + 3] * inv)};
        *(uint2*)&ctx[hoff + (size_t)qrow * DIM + d] = pA;
        *(uint2*)&ctx[hoff + (size_t)qrow * DIM + 32 + d] = pB;
    }
}

extern "C" void kernel_launch(void* const* d_in, const int* in_sizes, int n_in,
                              void* d_out, int out_size, void* d_ws, size_t ws_size,
                              hipStream_t stream) {
    const float* x = (const float*)d_in[0];
    const float* w_norm = (const float*)d_in[1];
    const float* Wq = (const float*)d_in[2];
    const float* Wk = (const float*)d_in[3];
    const float* Wv = (const float*)d_in[4];
    const float* Wo = (const float*)d_in[5];
    float* out = (float*)d_out;
    char* w8 = (char*)d_ws;

    const size_t MB = 1ull << 20;
    __bf16* xn = (__bf16*)(w8);               // [0,8)
    __bf16* wtq = (__bf16*)(w8 + 8 * MB);     // [8,10)
    __bf16* wtk = (__bf16*)(w8 + 10 * MB);    // [10,12)
    __bf16* wtv = (__bf16*)(w8 + 12 * MB);    // [12,14)
    __bf16* wto = (__bf16*)(w8 + 14 * MB);    // [14,16)
    __bf16* qb = (__bf16*)(w8 + 16 * MB);     // [16,24)
    __bf16* kb = (__bf16*)(w8 + 24 * MB);     // [24,32)
    __bf16* vtb = (__bf16*)(w8 + 32 * MB);    // [32,40)
    __bf16* ctx = (__bf16*)(w8 + 40 * MB);    // [40,48)
    float* cosT = (float*)(w8 + 48 * MB);     // 256KB
    float* sinT = cosT + SEQ * 32;            // 256KB

    wcvt_kernel<<<dim3(32, 32, 4), 256, 0, stream>>>(Wq, Wk, Wv, Wo, wtq, wtk, wtv, wto);
    rmsnorm_bf16<<<ROWS, 256, 0, stream>>>(x, w_norm, xn);
    rope_table_kernel<<<(SEQ * 32) / 256, 256, 0, stream>>>(cosT, sinT);

    gemm_qkv_kernel<<<768, 256, 0, stream>>>(xn, wtq, wtk, wtv, qb, kb, vtb, cosT, sinT);

    attn_fused_kernel<<<dim3(BATCH * NHEADS, 16), 256, 0, stream>>>(qb, kb, vtb, ctx);

    gemm_out_kernel<<<dim3(DIM / 128, ROWS / 128), 256, 0, stream>>>(ctx, wto, out);
}